// Round 6
// baseline (336.857 us; speedup 1.0000x reference)
//
#include <hip/hip_runtime.h>

// Problem constants (B=4, L=4096, E=512, H=16, D=32)
#define EMBED  512
#define NHEAD  16
#define HDIM   32
#define NBATCH 4
#define SEQ    4096
#define NROWS  (NBATCH * SEQ)   // 16384
#define FEPS   1e-6f

typedef __attribute__((ext_vector_type(8))) short short8;
typedef __attribute__((ext_vector_type(4))) float f32x4;

// ---- bf16 split helpers (RNE) ----
__device__ __forceinline__ short f2bf(float x) {
    unsigned u = __float_as_uint(x);
    u += 0x7FFFu + ((u >> 16) & 1u);
    return (short)(u >> 16);
}
__device__ __forceinline__ float bf2f(short h) {
    return __uint_as_float(((unsigned)(unsigned short)h) << 16);
}

// ---- all 4 weights split in one launch: seg = blockIdx.x>>8 ----
__global__ __launch_bounds__(256)
void convert_w4(const float* __restrict__ W0, const float* __restrict__ W1,
                const float* __restrict__ W2, const float* __restrict__ W3,
                short* __restrict__ H0, short* __restrict__ L0,
                short* __restrict__ H1, short* __restrict__ L1,
                short* __restrict__ H2, short* __restrict__ L2,
                short* __restrict__ H3, short* __restrict__ L3) {
    const int seg = blockIdx.x >> 8;
    const int i = ((blockIdx.x & 255) * 256 + threadIdx.x) * 4;
    const float* W = (seg == 0) ? W0 : (seg == 1) ? W1 : (seg == 2) ? W2 : W3;
    short* H = (seg == 0) ? H0 : (seg == 1) ? H1 : (seg == 2) ? H2 : H3;
    short* L = (seg == 0) ? L0 : (seg == 1) ? L1 : (seg == 2) ? L2 : L3;
    float4 v = *(const float4*)(W + i);
    short4 h, l;
    h.x = f2bf(v.x); l.x = f2bf(v.x - bf2f(h.x));
    h.y = f2bf(v.y); l.y = f2bf(v.y - bf2f(h.y));
    h.z = f2bf(v.z); l.z = f2bf(v.z - bf2f(h.z));
    h.w = f2bf(v.w); l.w = f2bf(v.w - bf2f(h.w));
    *(short4*)(H + i) = h;
    *(short4*)(L + i) = l;
}

// ---- fused QKV projection GEMM -------------------------------------------
// Round-5 proven structure: 128x128 tile, 4 waves 2x2, (256,2), fused 3 ops,
// y-major swizzle. NEW: term-major MFMA order (16 indep MFMAs between
// same-acc reuses -> hides MFMA dep latency). Q out = fp32 row-major;
// K,V out = TRANSPOSED split-bf16 (Kt[e][s], 4B/elem) for the kv kernel.
#define LDA 40   // padded LDS row (shorts)

__global__ __launch_bounds__(256, 2)
void qkv_gemm(const float* __restrict__ Aq, const float* __restrict__ Ak,
              const float* __restrict__ Av,
              const short* __restrict__ WqH, const short* __restrict__ WqL,
              const short* __restrict__ WkH, const short* __restrict__ WkL,
              const short* __restrict__ WvH, const short* __restrict__ WvL,
              float* __restrict__ Qb,
              short* __restrict__ KtH, short* __restrict__ KtL,
              short* __restrict__ VtH, short* __restrict__ VtL) {
    __shared__ short Ah[128][LDA];
    __shared__ short Al[128][LDA];

    const int tid  = threadIdx.x;
    const int lane = tid & 63;
    const int wave = tid >> 6;
    const int wm   = (wave >> 1) * 64;
    const int wn   = (wave & 1) * 64;
    const int l15  = lane & 15;
    const int kg   = lane >> 4;

    const int lin = blockIdx.x;
    const int op  = lin >> 9;                    // 0=q,1=k,2=v
    const int r_  = lin & 511;
    const int bn  = (r_ >> 7) * 128;             // y-major swizzle
    const int bm  = (r_ & 127) * 128;

    const float* A   = (op == 0) ? Aq  : (op == 1) ? Ak  : Av;
    const short* Whi = (op == 0) ? WqH : (op == 1) ? WkH : WvH;
    const short* Wlo = (op == 0) ? WqL : (op == 1) ? WkL : WvL;

    const int sr = tid >> 2;
    const int sk = (tid & 3) * 8;
    const float* Ap0 = A + (size_t)(bm + sr) * EMBED + sk;
    const float* Ap1 = Ap0 + (size_t)64 * EMBED;

    const short* Bh = Whi + (size_t)(bn + wn + l15) * EMBED + kg * 8;
    const short* Bl = Wlo + (size_t)(bn + wn + l15) * EMBED + kg * 8;

    f32x4 acc[4][4];
#pragma unroll
    for (int i = 0; i < 4; ++i)
#pragma unroll
        for (int j = 0; j < 4; ++j) acc[i][j] = (f32x4)0.0f;

#pragma unroll 1
    for (int k0 = 0; k0 < EMBED; k0 += 32) {
        float4 a0 = *(const float4*)(Ap0 + k0);
        float4 a1 = *(const float4*)(Ap0 + k0 + 4);
        float4 a2 = *(const float4*)(Ap1 + k0);
        float4 a3 = *(const float4*)(Ap1 + k0 + 4);
        short8 bh[4], bl[4];
#pragma unroll
        for (int j = 0; j < 4; ++j) {
            bh[j] = *(const short8*)(Bh + (size_t)j * 16 * EMBED + k0);
            bl[j] = *(const short8*)(Bl + (size_t)j * 16 * EMBED + k0);
        }
        __syncthreads();   // protect previous iteration's LDS reads
        {
            float v[8] = {a0.x, a0.y, a0.z, a0.w, a1.x, a1.y, a1.z, a1.w};
            short8 hv, lv;
#pragma unroll
            for (int q = 0; q < 8; ++q) {
                short hb = f2bf(v[q]);
                hv[q] = hb; lv[q] = f2bf(v[q] - bf2f(hb));
            }
            *(short8*)&Ah[sr][sk] = hv;
            *(short8*)&Al[sr][sk] = lv;
        }
        {
            float v[8] = {a2.x, a2.y, a2.z, a2.w, a3.x, a3.y, a3.z, a3.w};
            short8 hv, lv;
#pragma unroll
            for (int q = 0; q < 8; ++q) {
                short hb = f2bf(v[q]);
                hv[q] = hb; lv[q] = f2bf(v[q] - bf2f(hb));
            }
            *(short8*)&Ah[sr + 64][sk] = hv;
            *(short8*)&Al[sr + 64][sk] = lv;
        }
        __syncthreads();

        short8 ah[4], alr[4];
#pragma unroll
        for (int i = 0; i < 4; ++i) {
            ah[i]  = *(const short8*)&Ah[wm + i * 16 + l15][kg * 8];
            alr[i] = *(const short8*)&Al[wm + i * 16 + l15][kg * 8];
        }
        // term-major: 16 independent MFMAs between same-acc reuses
#pragma unroll
        for (int i = 0; i < 4; ++i)
#pragma unroll
            for (int j = 0; j < 4; ++j)
                acc[i][j] = __builtin_amdgcn_mfma_f32_16x16x32_bf16(ah[i], bh[j], acc[i][j], 0, 0, 0);
#pragma unroll
        for (int i = 0; i < 4; ++i)
#pragma unroll
            for (int j = 0; j < 4; ++j)
                acc[i][j] = __builtin_amdgcn_mfma_f32_16x16x32_bf16(ah[i], bl[j], acc[i][j], 0, 0, 0);
#pragma unroll
        for (int i = 0; i < 4; ++i)
#pragma unroll
            for (int j = 0; j < 4; ++j)
                acc[i][j] = __builtin_amdgcn_mfma_f32_16x16x32_bf16(alr[i], bh[j], acc[i][j], 0, 0, 0);
    }

    // ---- epilogue ----
    if (op == 0) {
        // Q: fp32 row-major scalar stores (round-2/5 proven, elu+1)
#pragma unroll
        for (int i = 0; i < 4; ++i)
#pragma unroll
            for (int j = 0; j < 4; ++j) {
                const int col = bn + wn + j * 16 + l15;
#pragma unroll
                for (int r = 0; r < 4; ++r) {
                    const int row = bm + wm + i * 16 + kg * 4 + r;
                    float vv = acc[i][j][r];
                    vv = (vv > 0.f) ? (vv + 1.f) : __expf(vv);
                    Qb[(size_t)row * EMBED + col] = vv;
                }
            }
    } else {
        // K/V: transposed split-bf16. T[col][row]: per lane ushort4 covers
        // 4 consecutive rows; 16 i-j stores collectively fill whole lines.
        short* TH = (op == 1) ? KtH : VtH;
        short* TL = (op == 1) ? KtL : VtL;
#pragma unroll
        for (int i = 0; i < 4; ++i)
#pragma unroll
            for (int j = 0; j < 4; ++j) {
                const int col  = bn + wn + j * 16 + l15;
                const int rowb = bm + wm + i * 16 + kg * 4;
                ushort4 hi4, lo4;
#pragma unroll
                for (int r = 0; r < 4; ++r) {
                    float vv = acc[i][j][r];
                    if (op == 1) vv = (vv > 0.f) ? (vv + 1.f) : __expf(vv);
                    else         vv = vv * (1.0f / (float)SEQ);
                    short hb = f2bf(vv);
                    ((unsigned short*)&hi4)[r] = (unsigned short)hb;
                    ((unsigned short*)&lo4)[r] = (unsigned short)f2bf(vv - bf2f(hb));
                }
                *(ushort4*)(TH + (size_t)col * NROWS + rowb) = hi4;
                *(ushort4*)(TL + (size_t)col * NROWS + rowb) = lo4;
            }
    }
}

// ---- merge GEMM: round-5 structure + term-major MFMA order ----------------
__global__ __launch_bounds__(256, 2)
void merge_gemm(const float* __restrict__ A, const short* __restrict__ Whi,
                const short* __restrict__ Wlo, float* __restrict__ C) {
    __shared__ short Ah[128][LDA];
    __shared__ short Al[128][LDA];

    const int tid  = threadIdx.x;
    const int lane = tid & 63;
    const int wave = tid >> 6;
    const int wm   = (wave >> 1) * 64;
    const int wn   = (wave & 1) * 64;
    const int l15  = lane & 15;
    const int kg   = lane >> 4;

    const int lin = blockIdx.x;
    const int bn  = (lin >> 7) * 128;
    const int bm  = (lin & 127) * 128;

    const int sr = tid >> 2;
    const int sk = (tid & 3) * 8;
    const float* Ap0 = A + (size_t)(bm + sr) * EMBED + sk;
    const float* Ap1 = Ap0 + (size_t)64 * EMBED;

    const short* Bh = Whi + (size_t)(bn + wn + l15) * EMBED + kg * 8;
    const short* Bl = Wlo + (size_t)(bn + wn + l15) * EMBED + kg * 8;

    f32x4 acc[4][4];
#pragma unroll
    for (int i = 0; i < 4; ++i)
#pragma unroll
        for (int j = 0; j < 4; ++j) acc[i][j] = (f32x4)0.0f;

#pragma unroll 1
    for (int k0 = 0; k0 < EMBED; k0 += 32) {
        float4 a0 = *(const float4*)(Ap0 + k0);
        float4 a1 = *(const float4*)(Ap0 + k0 + 4);
        float4 a2 = *(const float4*)(Ap1 + k0);
        float4 a3 = *(const float4*)(Ap1 + k0 + 4);
        short8 bh[4], bl[4];
#pragma unroll
        for (int j = 0; j < 4; ++j) {
            bh[j] = *(const short8*)(Bh + (size_t)j * 16 * EMBED + k0);
            bl[j] = *(const short8*)(Bl + (size_t)j * 16 * EMBED + k0);
        }
        __syncthreads();
        {
            float v[8] = {a0.x, a0.y, a0.z, a0.w, a1.x, a1.y, a1.z, a1.w};
            short8 hv, lv;
#pragma unroll
            for (int q = 0; q < 8; ++q) {
                short hb = f2bf(v[q]);
                hv[q] = hb; lv[q] = f2bf(v[q] - bf2f(hb));
            }
            *(short8*)&Ah[sr][sk] = hv;
            *(short8*)&Al[sr][sk] = lv;
        }
        {
            float v[8] = {a2.x, a2.y, a2.z, a2.w, a3.x, a3.y, a3.z, a3.w};
            short8 hv, lv;
#pragma unroll
            for (int q = 0; q < 8; ++q) {
                short hb = f2bf(v[q]);
                hv[q] = hb; lv[q] = f2bf(v[q] - bf2f(hb));
            }
            *(short8*)&Ah[sr + 64][sk] = hv;
            *(short8*)&Al[sr + 64][sk] = lv;
        }
        __syncthreads();

        short8 ah[4], alr[4];
#pragma unroll
        for (int i = 0; i < 4; ++i) {
            ah[i]  = *(const short8*)&Ah[wm + i * 16 + l15][kg * 8];
            alr[i] = *(const short8*)&Al[wm + i * 16 + l15][kg * 8];
        }
#pragma unroll
        for (int i = 0; i < 4; ++i)
#pragma unroll
            for (int j = 0; j < 4; ++j)
                acc[i][j] = __builtin_amdgcn_mfma_f32_16x16x32_bf16(ah[i], bh[j], acc[i][j], 0, 0, 0);
#pragma unroll
        for (int i = 0; i < 4; ++i)
#pragma unroll
            for (int j = 0; j < 4; ++j)
                acc[i][j] = __builtin_amdgcn_mfma_f32_16x16x32_bf16(ah[i], bl[j], acc[i][j], 0, 0, 0);
#pragma unroll
        for (int i = 0; i < 4; ++i)
#pragma unroll
            for (int j = 0; j < 4; ++j)
                acc[i][j] = __builtin_amdgcn_mfma_f32_16x16x32_bf16(alr[i], bh[j], acc[i][j], 0, 0, 0);
    }

#pragma unroll
    for (int i = 0; i < 4; ++i)
#pragma unroll
        for (int j = 0; j < 4; ++j) {
            const int col = bn + wn + j * 16 + l15;
#pragma unroll
            for (int r = 0; r < 4; ++r) {
                const int row = bm + wm + i * 16 + kg * 4 + r;
                C[(size_t)row * EMBED + col] = acc[i][j][r];
            }
        }
}

// ---- KV + Ksum from TRANSPOSED split-bf16 K,V: no LDS, no conversion ------
// A-frag (d,s) and B-frag (e,s) are direct contiguous short8 global loads.
// grid (8 s-chunks, 64 bh); block = 512 s rows, wave = 128 (4 iters of 32).
// Reduce tail identical to round-5 (same fragment->element mapping).
__global__ __launch_bounds__(256)
void kv_ksum_t(const short* __restrict__ KtH, const short* __restrict__ KtL,
               const short* __restrict__ VtH, const short* __restrict__ VtL,
               float* __restrict__ KV, float* __restrict__ Ksum) {
    __shared__ float red[4 * 1056];

    const int bh_ = blockIdx.y;
    const int b = bh_ >> 4, h = bh_ & 15;
    const int t = threadIdx.x;
    const int lane = t & 63, wave = t >> 6;
    const int l15 = lane & 15, kg = lane >> 4;

    const int sbase = b * SEQ + blockIdx.x * 512 + wave * 128;

    f32x4 kvacc[2][2], ksacc[2];
#pragma unroll
    for (int i = 0; i < 2; ++i) {
        ksacc[i] = (f32x4)0.0f;
#pragma unroll
        for (int j = 0; j < 2; ++j) kvacc[i][j] = (f32x4)0.0f;
    }
    short8 ones;
#pragma unroll
    for (int q = 0; q < 8; ++q) ones[q] = (short)0x3F80;   // bf16 1.0

    // per-fragment row bases (d/e = h*32 + i*16 + l15)
    size_t rbase[2];
#pragma unroll
    for (int i = 0; i < 2; ++i)
        rbase[i] = (size_t)(h * HDIM + i * 16 + l15) * NROWS + sbase + kg * 8;

#pragma unroll 2
    for (int s = 0; s < 128; s += 32) {
        short8 kah[2], kal[2], vbh[2], vbl[2];
#pragma unroll
        for (int i = 0; i < 2; ++i) {
            kah[i] = *(const short8*)(KtH + rbase[i] + s);
            kal[i] = *(const short8*)(KtL + rbase[i] + s);
            vbh[i] = *(const short8*)(VtH + rbase[i] + s);
            vbl[i] = *(const short8*)(VtL + rbase[i] + s);
        }
#pragma unroll
        for (int i = 0; i < 2; ++i)
#pragma unroll
            for (int j = 0; j < 2; ++j)
                kvacc[i][j] = __builtin_amdgcn_mfma_f32_16x16x32_bf16(kah[i], vbh[j], kvacc[i][j], 0, 0, 0);
#pragma unroll
        for (int i = 0; i < 2; ++i)
#pragma unroll
            for (int j = 0; j < 2; ++j)
                kvacc[i][j] = __builtin_amdgcn_mfma_f32_16x16x32_bf16(kah[i], vbl[j], kvacc[i][j], 0, 0, 0);
#pragma unroll
        for (int i = 0; i < 2; ++i)
#pragma unroll
            for (int j = 0; j < 2; ++j)
                kvacc[i][j] = __builtin_amdgcn_mfma_f32_16x16x32_bf16(kal[i], vbh[j], kvacc[i][j], 0, 0, 0);
#pragma unroll
        for (int i = 0; i < 2; ++i) {
            ksacc[i] = __builtin_amdgcn_mfma_f32_16x16x32_bf16(kah[i], ones, ksacc[i], 0, 0, 0);
            ksacc[i] = __builtin_amdgcn_mfma_f32_16x16x32_bf16(kal[i], ones, ksacc[i], 0, 0, 0);
        }
    }

    // ---- cross-wave reduce in LDS, one atomic per element (round-5 tail) --
    float* myred = red + wave * 1056;
#pragma unroll
    for (int i = 0; i < 2; ++i)
#pragma unroll
        for (int j = 0; j < 2; ++j)
#pragma unroll
            for (int r = 0; r < 4; ++r)
                myred[(i * 16 + kg * 4 + r) * 32 + j * 16 + l15] = kvacc[i][j][r];
    if (l15 == 0) {
#pragma unroll
        for (int i = 0; i < 2; ++i)
#pragma unroll
            for (int r = 0; r < 4; ++r)
                myred[1024 + i * 16 + kg * 4 + r] = ksacc[i][r];
    }
    __syncthreads();
    float* kvout = KV + (size_t)bh_ * 1024;
    for (int idx = t; idx < 1024; idx += 256) {
        float s4 = red[idx] + red[1056 + idx] + red[2112 + idx] + red[3168 + idx];
        atomicAdd(&kvout[idx], s4);
    }
    if (t < 32) {
        float s4 = red[1024 + t] + red[1056 + 1024 + t] + red[2112 + 1024 + t] + red[3168 + 1024 + t];
        atomicAdd(&Ksum[bh_ * 32 + t], s4);
    }
}

// ---- message (in place): Q[l,h,:] <- (SEQ/(Q.Ksum+eps)) * Q @ KV[b,h] ----
__global__ __launch_bounds__(512)
void message_kernel(float* __restrict__ Q, const float* __restrict__ KV,
                    const float* __restrict__ Ksum) {
    const int blk  = blockIdx.x;
    const int row0 = blk * 4;
    const int b    = row0 >> 12;
    const int t    = threadIdx.x;
    const int h    = t >> 5, e = t & 31;

    __shared__ float q[4][EMBED];
    __shared__ float ks[EMBED];
    ks[t] = Ksum[b * EMBED + t];
#pragma unroll
    for (int r = 0; r < 4; ++r) q[r][t] = Q[(size_t)(row0 + r) * EMBED + t];

    const float* kvh = KV + (size_t)(b * NHEAD + h) * HDIM * HDIM + e;
    float kc[HDIM];
#pragma unroll
    for (int d = 0; d < HDIM; ++d) kc[d] = kvh[d * HDIM];
    __syncthreads();

#pragma unroll
    for (int r = 0; r < 4; ++r) {
        float zden = FEPS, m = 0.f;
#pragma unroll
        for (int d = 0; d < HDIM; ++d) {
            float qd = q[r][h * HDIM + d];
            zden = fmaf(qd, ks[h * HDIM + d], zden);
            m    = fmaf(qd, kc[d], m);
        }
        Q[(size_t)(row0 + r) * EMBED + t] = m * ((float)SEQ / zden);
    }
}

// ---- launch ----
extern "C" void kernel_launch(void* const* d_in, const int* in_sizes, int n_in,
                              void* d_out, int out_size, void* d_ws, size_t ws_size,
                              hipStream_t stream) {
    const float* query = (const float*)d_in[0];
    const float* key   = (const float*)d_in[1];
    const float* value = (const float*)d_in[2];
    const float* Wq    = (const float*)d_in[3];
    const float* Wk    = (const float*)d_in[4];
    const float* Wv    = (const float*)d_in[5];
    const float* Wm    = (const float*)d_in[6];
    float* out = (float*)d_out;

    const size_t S = (size_t)NROWS * EMBED;       // 8.39M elems
    float* ws  = (float*)d_ws;
    float* Qb  = ws;                              // fp32, in-place message out
    short* KtH = (short*)(Qb + S);                // transposed split K
    short* KtL = KtH + S;
    short* VtH = KtL + S;                         // transposed split V
    short* VtL = VtH + S;
    float* KVb = (float*)(VtL + S);               // 64*1024
    float* KSb = KVb + 64 * 1024;                 // 64*32
    short* wsp = (short*)(KSb + 64 * HDIM);
    const int WN = EMBED * EMBED;
    short* WqH = wsp;            short* WqL = wsp + WN;
    short* WkH = wsp + 2 * WN;   short* WkL = wsp + 3 * WN;
    short* WvH = wsp + 4 * WN;   short* WvL = wsp + 5 * WN;
    short* WmH = wsp + 6 * WN;   short* WmL = wsp + 7 * WN;

    hipMemsetAsync(KVb, 0, (64 * 1024 + 64 * HDIM) * sizeof(float), stream);

    convert_w4<<<1024, 256, 0, stream>>>(Wq, Wk, Wv, Wm,
                                         WqH, WqL, WkH, WkL,
                                         WvH, WvL, WmH, WmL);

    qkv_gemm<<<1536, 256, 0, stream>>>(query, key, value,
                                       WqH, WqL, WkH, WkL, WvH, WvL,
                                       Qb, KtH, KtL, VtH, VtL);

    kv_ksum_t<<<dim3(8, 64), 256, 0, stream>>>(KtH, KtL, VtH, VtL, KVb, KSb);
    message_kernel<<<NROWS / 4, 512, 0, stream>>>(Qb, KVb, KSb);

    merge_gemm<<<512, 256, 0, stream>>>(Qb, WmH, WmL, out);
}